// Round 1
// baseline (57598.120 us; speedup 1.0000x reference)
//
#include <hip/hip_runtime.h>
#include <cmath>

// Problem dims (fixed by reference)
#define B_   128
#define T_   500
#define MEL_ 80
#define RED_ 2
#define D_   256   // decoder dim
#define E_   128   // encoder/prenet-out dim
#define PRE_ 256   // prenet hidden
#define L_   256   // encoder length
#define TPB  1024
#define ENC_STRIDE 264   // padded ushort stride per enc row (264*2=528B, 16B aligned)

__device__ __forceinline__ float sigmoidf_(float x) { return 1.f / (1.f + expf(-x)); }
__device__ __forceinline__ float bflo(unsigned u) { return __uint_as_float(u << 16); }
__device__ __forceinline__ float bfhi(unsigned u) { return __uint_as_float(u & 0xFFFF0000u); }
__device__ __forceinline__ float bfval(ushort v) { return __uint_as_float(((unsigned)v) << 16); }
__device__ __forceinline__ ushort f2bf(float f) {
    unsigned u = __float_as_uint(f);
    return (ushort)((u + 0x7FFFu + ((u >> 16) & 1u)) >> 16);
}

// accumulate 8 bf16 (one uint4) against 8 fp32
__device__ __forceinline__ float acc8(uint4 u, const float* vv, float s) {
    s = fmaf(bflo(u.x), vv[0], s);
    s = fmaf(bfhi(u.x), vv[1], s);
    s = fmaf(bflo(u.y), vv[2], s);
    s = fmaf(bfhi(u.y), vv[3], s);
    s = fmaf(bflo(u.z), vv[4], s);
    s = fmaf(bfhi(u.z), vv[5], s);
    s = fmaf(bflo(u.w), vv[6], s);
    s = fmaf(bfhi(u.w), vv[7], s);
    return s;
}

// Packed ("task-major") bf16 weights: chunk c (16B = 8 elems) of task t lives at
// uint4 index (c*NT + t). Lane-consecutive tasks -> consecutive 16B chunks ->
// every wave load is 1KB fully contiguous (perfect L1/L2 line utilization).
// 4 independent accumulators break the fmaf dependency chain (ILP + MLP).
template<int CH, int NT>
__device__ __forceinline__ float dotpk(const ushort* __restrict__ wp, int t, const float* v) {
    const uint4* w = reinterpret_cast<const uint4*>(wp) + t;
    float s0 = 0.f, s1 = 0.f, s2 = 0.f, s3 = 0.f;
#pragma unroll
    for (int c = 0; c < (CH & ~3); c += 4) {
        uint4 u0 = w[(c + 0) * NT];
        uint4 u1 = w[(c + 1) * NT];
        uint4 u2 = w[(c + 2) * NT];
        uint4 u3 = w[(c + 3) * NT];
        s0 = acc8(u0, v + (c + 0) * 8, s0);
        s1 = acc8(u1, v + (c + 1) * 8, s1);
        s2 = acc8(u2, v + (c + 2) * 8, s2);
        s3 = acc8(u3, v + (c + 3) * 8, s3);
    }
    if (CH & 2) {
        constexpr int c = CH & ~3;
        uint4 u0 = w[(c + 0) * NT];
        uint4 u1 = w[(c + 1) * NT];
        s0 = acc8(u0, v + (c + 0) * 8, s0);
        s1 = acc8(u1, v + (c + 1) * 8, s1);
    }
    return (s0 + s1) + (s2 + s3);
}

// bf16 row in LDS (s_enc) . fp32 vector — unchanged path for score phase
__device__ __forceinline__ float dotbf(const ushort* __restrict__ wrow,
                                       const float* v, int k8) {
    const uint4* w = reinterpret_cast<const uint4*>(wrow);
    float s = 0.f;
#pragma unroll 8
    for (int k = 0; k < k8; ++k) {
        uint4 u = w[k];
        const float* vv = v + k * 8;
        s = fmaf(bflo(u.x), vv[0], s);
        s = fmaf(bfhi(u.x), vv[1], s);
        s = fmaf(bflo(u.y), vv[2], s);
        s = fmaf(bfhi(u.y), vv[3], s);
        s = fmaf(bflo(u.z), vv[4], s);
        s = fmaf(bfhi(u.z), vv[5], s);
        s = fmaf(bflo(u.w), vv[6], s);
        s = fmaf(bfhi(u.w), vv[7], s);
    }
    return s;
}

// fp32 [rows x rowLen] -> bf16 task-major packed layout.
// dst[(c*NT + t)*8 + e] = bf16(src[(t/dA)*mA + (t%dA)*mB + c*8 + e])
__global__ void pack_bf16_kernel(const float* __restrict__ src,
                                 ushort* __restrict__ dst,
                                 int NT, int CH, int dA, int mA, int mB) {
    int i = blockIdx.x * blockDim.x + threadIdx.x;
    int n = NT * CH * 8;
    if (i >= n) return;
    int c = i / (NT * 8);
    int r = i - c * (NT * 8);
    int t = r >> 3;
    int e = r & 7;
    dst[i] = f2bf(src[(t / dA) * mA + (t % dA) * mB + c * 8 + e]);
}

// Persistent decoder: 1 block per batch element, enc[b] resident in LDS,
// bf16 packed weights L2-resident (2.55 MB < 4 MB/XCD), 16 waves/CU.
__global__ __launch_bounds__(TPB) void decoder_persist(
    const float* __restrict__ dec_input,   // [B,T,MEL] fp32
    const float* __restrict__ enc_output,  // [B,L,D]  fp32 (converted in-kernel)
    const ushort* __restrict__ pre_w1, const float* __restrict__ pre_b1,
    const ushort* __restrict__ pre_w2, const float* __restrict__ pre_b2,
    const ushort* __restrict__ attn_wih, const ushort* __restrict__ attn_whh,
    const float* __restrict__ attn_bih, const float* __restrict__ attn_bhh,
    const ushort* __restrict__ proj1_w, const float* __restrict__ proj1_b,
    const ushort* __restrict__ rnn1_wih, const ushort* __restrict__ rnn1_whh,
    const float* __restrict__ rnn1_bih, const float* __restrict__ rnn1_bhh,
    const ushort* __restrict__ rnn2_wih, const ushort* __restrict__ rnn2_whh,
    const float* __restrict__ rnn2_bih, const float* __restrict__ rnn2_bhh,
    const ushort* __restrict__ proj2_w, const float* __restrict__ proj2_b,
    float* __restrict__ mel_out,   // [B, T*RED, MEL]
    float* __restrict__ align_out) // [B, L, T]
{
    const int b    = blockIdx.x;
    const int tid  = threadIdx.x;
    const int lane = tid & 63;
    const int wv   = tid >> 6;

    // LDS total ~158.5 KB (gfx950 has 160 KB/CU)
    __shared__ __align__(16) ushort s_enc[L_ * ENC_STRIDE];  // 135168 B
    __shared__ __align__(16) float A[1536];                  // partial buf A
    __shared__ __align__(16) float Bp[1536];                 // partial buf B
    __shared__ __align__(16) float s_frame[MEL_];
    __shared__ __align__(16) float s_x1[PRE_];
    __shared__ __align__(16) float s_x[E_];
    __shared__ __align__(16) float s_ha[D_];
    __shared__ __align__(16) float s_h1[D_];
    __shared__ __align__(16) float s_h2[D_];
    __shared__ __align__(16) float s_dec[D_];
    __shared__ __align__(16) float s_y1[D_];
    __shared__ __align__(16) float s_y2[D_];
    __shared__ __align__(16) float s_cat[2 * D_];
    __shared__ __align__(16) float s_al[L_];
    __shared__ float s_pmax[4];
    __shared__ float s_psum[4];

    // ---- load + convert enc[b] fp32 -> bf16 LDS (padded rows) ----
    {
        const float4* eb = reinterpret_cast<const float4*>(enc_output + (size_t)b * L_ * D_);
        for (int i = tid; i < (L_ * D_) / 4; i += TPB) {
            float4 f = eb[i];
            int row = i >> 6;   // 64 float4 per 256-elem row
            int c4  = i & 63;
            uint2 pk;
            pk.x = (unsigned)f2bf(f.x) | ((unsigned)f2bf(f.y) << 16);
            pk.y = (unsigned)f2bf(f.z) | ((unsigned)f2bf(f.w) << 16);
            *reinterpret_cast<uint2*>(s_enc + row * ENC_STRIDE + c4 * 4) = pk;
        }
    }
    if (tid < D_) { s_ha[tid] = 0.f; s_h1[tid] = 0.f; s_h2[tid] = 0.f; }
    __syncthreads();

    // GRU gate task phase: 3072 half-dots (K=128), 3 per thread, balanced.
    // task t<1536: wih row t>>1, half t&1; t>=1536: whh likewise (packed layouts match).
    auto gru_gates = [&](const ushort* wihP, const ushort* whhP,
                         const float* xin, const float* h) {
        for (int task = tid; task < 3072; task += TPB) {
            if (task < 1536) {
                A[task] = dotpk<16, 1536>(wihP, task, xin + (task & 1) * 128);
            } else {
                int u = task - 1536;
                Bp[u] = dotpk<16, 1536>(whhP, u, h + (u & 1) * 128);
            }
        }
    };
    auto gru_combine = [&](const float* bih, const float* bhh,
                           float* h, const float* xin, float* y) {
        if (tid < D_) {
            int t0 = tid;
            float gir = A[2 * t0] + A[2 * t0 + 1] + bih[t0];
            float giz = A[2 * (D_ + t0)] + A[2 * (D_ + t0) + 1] + bih[D_ + t0];
            float gin = A[2 * (2 * D_ + t0)] + A[2 * (2 * D_ + t0) + 1] + bih[2 * D_ + t0];
            float ghr = Bp[2 * t0] + Bp[2 * t0 + 1] + bhh[t0];
            float ghz = Bp[2 * (D_ + t0)] + Bp[2 * (D_ + t0) + 1] + bhh[D_ + t0];
            float ghn = Bp[2 * (2 * D_ + t0)] + Bp[2 * (2 * D_ + t0) + 1] + bhh[2 * D_ + t0];
            float r = sigmoidf_(gir + ghr);
            float z = sigmoidf_(giz + ghz);
            float n = tanhf(gin + r * ghn);
            float hn = (1.f - z) * n + z * h[t0];
            h[t0] = hn;
            y[t0] = xin[t0] + hn;
        }
    };

    for (int t = 0; t < T_; ++t) {
        // [1] frame
        if (tid < MEL_)
            s_frame[tid] = dec_input[((size_t)b * T_ + t) * MEL_ + tid];
        __syncthreads();

        // [2] prenet1: 256 rows, K=80 (CH=10)
        if (tid < PRE_)
            s_x1[tid] = fmaxf(dotpk<10, 256>(pre_w1, tid, s_frame) + pre_b1[tid], 0.f);
        __syncthreads();

        // [3] prenet2 partials: 128 rows, K=256 split 8-way (32 elems = CH 4 each)
        {
            int p = tid >> 7, j = tid & 127;
            A[p * 128 + j] = dotpk<4, 1024>(pre_w2, tid, s_x1 + p * 32);
        }
        __syncthreads();
        // [4] prenet2 combine
        if (tid < E_) {
            float s = pre_b2[tid];
#pragma unroll
            for (int p = 0; p < 8; ++p) s += A[p * 128 + tid];
            s_x[tid] = fmaxf(s, 0.f);
        }
        __syncthreads();

        // [5] attn gates: gh halves -> Bp[0..1535]; gi full rows (K=128) -> A[0..767]
        for (int task = tid; task < 2304; task += TPB) {
            if (task < 1536) {
                Bp[task] = dotpk<16, 1536>(attn_whh, task, s_ha + (task & 1) * 128);
            } else {
                int r2 = task - 1536;
                A[r2] = dotpk<16, 768>(attn_wih, r2, s_x);
            }
        }
        __syncthreads();
        // [6] attn GRU combine
        if (tid < D_) {
            float gir = A[tid] + attn_bih[tid];
            float giz = A[D_ + tid] + attn_bih[D_ + tid];
            float gin = A[2 * D_ + tid] + attn_bih[2 * D_ + tid];
            float ghr = Bp[2 * tid] + Bp[2 * tid + 1] + attn_bhh[tid];
            float ghz = Bp[2 * (D_ + tid)] + Bp[2 * (D_ + tid) + 1] + attn_bhh[D_ + tid];
            float ghn = Bp[2 * (2 * D_ + tid)] + Bp[2 * (2 * D_ + tid) + 1] + attn_bhh[2 * D_ + tid];
            float r = sigmoidf_(gir + ghr);
            float z = sigmoidf_(giz + ghz);
            float n = tanhf(gin + r * ghn);
            s_ha[tid] = (1.f - z) * n + z * s_ha[tid];
        }
        __syncthreads();

        // [7] scores partials: 256 rows x 4-way K-split over LDS enc
        {
            int p = tid >> 8, l = tid & 255;
            A[p * 256 + l] = dotbf(s_enc + l * ENC_STRIDE + p * 64, s_ha + p * 64, 8);
        }
        __syncthreads();
        float sc = 0.f, e = 0.f;
        // [8] finalize score + block max
        if (tid < L_) {
            sc = A[tid] + A[256 + tid] + A[512 + tid] + A[768 + tid];
            float m = sc;
            for (int o = 32; o > 0; o >>= 1) m = fmaxf(m, __shfl_xor(m, o, 64));
            if (lane == 0) s_pmax[wv] = m;
        }
        __syncthreads();
        // [9] exp + block sum
        if (tid < L_) {
            float mm = fmaxf(fmaxf(s_pmax[0], s_pmax[1]), fmaxf(s_pmax[2], s_pmax[3]));
            e = expf(sc - mm);
            float sm = e;
            for (int o = 32; o > 0; o >>= 1) sm += __shfl_xor(sm, o, 64);
            if (lane == 0) s_psum[wv] = sm;
        }
        __syncthreads();
        // [10] alignment
        if (tid < L_) {
            float denom = s_psum[0] + s_psum[1] + s_psum[2] + s_psum[3];
            float al = e / denom;
            s_al[tid] = al;
            align_out[((size_t)b * L_ + tid) * T_ + t] = al;
        }
        __syncthreads();

        // [11] ctx partials: 256 cols x 4-way L-split over LDS enc
        {
            int p = tid >> 8, d = tid & 255;
            const ushort* base = s_enc + (p * 64) * ENC_STRIDE + d;
            const float* alp = s_al + p * 64;
            float c = 0.f;
#pragma unroll 8
            for (int l = 0; l < 64; ++l)
                c = fmaf(alp[l], bfval(base[l * ENC_STRIDE]), c);
            A[p * 256 + d] = c;
        }
        __syncthreads();
        // [12] ctx combine -> cat
        if (tid < D_) {
            float c = A[tid] + A[256 + tid] + A[512 + tid] + A[768 + tid];
            s_cat[tid]      = c;
            s_cat[D_ + tid] = s_ha[tid];
        }
        __syncthreads();

        // [13] proj1 partials: 256 rows, K=512 split 4-way (CH=16 each)
        {
            int p = tid >> 8;
            A[tid] = dotpk<16, 1024>(proj1_w, tid, s_cat + p * 128);
        }
        __syncthreads();
        // [14] proj1 combine
        if (tid < D_)
            s_dec[tid] = A[tid] + A[256 + tid] + A[512 + tid] + A[768 + tid] + proj1_b[tid];
        __syncthreads();

        // [15][16] rnn1
        gru_gates(rnn1_wih, rnn1_whh, s_dec, s_h1);
        __syncthreads();
        gru_combine(rnn1_bih, rnn1_bhh, s_h1, s_dec, s_y1);
        __syncthreads();

        // [17][18] rnn2
        gru_gates(rnn2_wih, rnn2_whh, s_y1, s_h2);
        __syncthreads();
        gru_combine(rnn2_bih, rnn2_bhh, s_h2, s_y1, s_y2);
        __syncthreads();

        // [19] proj2 partials: 160 rows, K=256 split 4-way (640 tasks, CH=8)
        if (tid < 640) {
            A[tid] = dotpk<8, 640>(proj2_w, tid, s_y2 + (tid & 3) * 64);
        }
        __syncthreads();
        // proj2 combine + mel store (no trailing barrier needed: next writes to A
        // are 2 barriers away)
        if (tid < MEL_ * RED_) {
            float s = A[4 * tid] + A[4 * tid + 1] + A[4 * tid + 2] + A[4 * tid + 3] + proj2_b[tid];
            mel_out[(size_t)b * (T_ * RED_ * MEL_) + (size_t)t * (MEL_ * RED_) + tid] = s;
        }
    }
}

extern "C" void kernel_launch(void* const* d_in, const int* in_sizes, int n_in,
                              void* d_out, int out_size, void* d_ws, size_t ws_size,
                              hipStream_t stream) {
    const float* dec_input = (const float*)d_in[0];
    const float* enc_output= (const float*)d_in[1];
    const float* pre_w1    = (const float*)d_in[2];
    const float* pre_b1    = (const float*)d_in[3];
    const float* pre_w2    = (const float*)d_in[4];
    const float* pre_b2    = (const float*)d_in[5];
    const float* attn_wih  = (const float*)d_in[6];
    const float* attn_whh  = (const float*)d_in[7];
    const float* attn_bih  = (const float*)d_in[8];
    const float* attn_bhh  = (const float*)d_in[9];
    const float* proj1_w   = (const float*)d_in[10];
    const float* proj1_b   = (const float*)d_in[11];
    const float* rnn1_wih  = (const float*)d_in[12];
    const float* rnn1_whh  = (const float*)d_in[13];
    const float* rnn1_bih  = (const float*)d_in[14];
    const float* rnn1_bhh  = (const float*)d_in[15];
    const float* rnn2_wih  = (const float*)d_in[16];
    const float* rnn2_whh  = (const float*)d_in[17];
    const float* rnn2_bih  = (const float*)d_in[18];
    const float* rnn2_bhh  = (const float*)d_in[19];
    const float* proj2_w   = (const float*)d_in[20];
    const float* proj2_b   = (const float*)d_in[21];

    float* mel   = (float*)d_out;
    float* align = (float*)d_out + (size_t)B_ * T_ * RED_ * MEL_;

    // bf16 packed weight scratch (element counts — identical totals as source)
    const int n_pre_w1   = PRE_ * MEL_;        // 256*80
    const int n_pre_w2   = E_ * PRE_;          // 128*256
    const int n_attn_wih = 3 * D_ * E_;        // 768*128
    const int n_attn_whh = 3 * D_ * D_;        // 768*256
    const int n_proj1    = D_ * 2 * D_;        // 256*512
    const int n_rnn_w    = 3 * D_ * D_;        // 768*256
    const int n_proj2    = MEL_ * RED_ * D_;   // 160*256

    ushort* w = (ushort*)d_ws;
    ushort* c_pre_w1   = w; w += n_pre_w1;
    ushort* c_pre_w2   = w; w += n_pre_w2;
    ushort* c_attn_wih = w; w += n_attn_wih;
    ushort* c_attn_whh = w; w += n_attn_whh;
    ushort* c_proj1    = w; w += n_proj1;
    ushort* c_rnn1_wih = w; w += n_rnn_w;
    ushort* c_rnn1_whh = w; w += n_rnn_w;
    ushort* c_rnn2_wih = w; w += n_rnn_w;
    ushort* c_rnn2_whh = w; w += n_rnn_w;
    ushort* c_proj2    = w; w += n_proj2;

    // Task-major pack: dst[(c*NT+t)*8+e] = bf16(src[(t/dA)*mA + (t%dA)*mB + c*8 + e])
    auto pack = [&](const float* src, ushort* dst, int NT, int CH, int dA, int mA, int mB) {
        int n = NT * CH * 8;
        pack_bf16_kernel<<<dim3((n + 255) / 256), dim3(256), 0, stream>>>(
            src, dst, NT, CH, dA, mA, mB);
    };
    pack(pre_w1,   c_pre_w1,   256,  10, 1,   80,  0);    // row t, K=80
    pack(pre_w2,   c_pre_w2,   1024, 4,  128, 32,  256);  // row=t&127, p=t>>7 (32-elem sub)
    pack(attn_wih, c_attn_wih, 768,  16, 1,   128, 0);    // row t, K=128
    pack(attn_whh, c_attn_whh, 1536, 16, 2,   256, 128);  // row=t>>1, half=t&1
    pack(proj1_w,  c_proj1,    1024, 16, 256, 128, 512);  // row=t&255, p=t>>8 (128-elem sub)
    pack(rnn1_wih, c_rnn1_wih, 1536, 16, 2,   256, 128);
    pack(rnn1_whh, c_rnn1_whh, 1536, 16, 2,   256, 128);
    pack(rnn2_wih, c_rnn2_wih, 1536, 16, 2,   256, 128);
    pack(rnn2_whh, c_rnn2_whh, 1536, 16, 2,   256, 128);
    pack(proj2_w,  c_proj2,    640,  8,  4,   256, 64);   // row=t>>2, p=t&3 (64-elem sub)

    decoder_persist<<<dim3(B_), dim3(TPB), 0, stream>>>(
        dec_input, enc_output,
        c_pre_w1, pre_b1, c_pre_w2, pre_b2,
        c_attn_wih, c_attn_whh, attn_bih, attn_bhh,
        c_proj1, proj1_b,
        c_rnn1_wih, c_rnn1_whh, rnn1_bih, rnn1_bhh,
        c_rnn2_wih, c_rnn2_whh, rnn2_bih, rnn2_bhh,
        c_proj2, proj2_b,
        mel, align);
}

// Round 2
// 21178.781 us; speedup vs baseline: 2.7196x; 2.7196x over previous
//
#include <hip/hip_runtime.h>
#include <cmath>

// Problem dims (fixed by reference)
#define B_   128
#define T_   500
#define MEL_ 80
#define RED_ 2
#define D_   256   // decoder dim
#define E_   128   // encoder/prenet-out dim
#define PRE_ 256   // prenet hidden
#define L_   256   // encoder length
#define TPB  1024
#define ENC_STRIDE 264   // padded ushort stride per enc row (264*2=528B, 16B aligned)

__device__ __forceinline__ float sigmoidf_(float x) { return 1.f / (1.f + expf(-x)); }
__device__ __forceinline__ float bflo(unsigned u) { return __uint_as_float(u << 16); }
__device__ __forceinline__ float bfhi(unsigned u) { return __uint_as_float(u & 0xFFFF0000u); }
__device__ __forceinline__ float bfval(ushort v) { return __uint_as_float(((unsigned)v) << 16); }
__device__ __forceinline__ ushort f2bf(float f) {
    unsigned u = __float_as_uint(f);
    return (ushort)((u + 0x7FFFu + ((u >> 16) & 1u)) >> 16);
}

// accumulate 8 bf16 (one uint4) against 8 fp32
__device__ __forceinline__ float acc8(uint4 u, const float* vv, float s) {
    s = fmaf(bflo(u.x), vv[0], s);
    s = fmaf(bfhi(u.x), vv[1], s);
    s = fmaf(bflo(u.y), vv[2], s);
    s = fmaf(bfhi(u.y), vv[3], s);
    s = fmaf(bflo(u.z), vv[4], s);
    s = fmaf(bfhi(u.z), vv[5], s);
    s = fmaf(bflo(u.w), vv[6], s);
    s = fmaf(bfhi(u.w), vv[7], s);
    return s;
}

// Wave-group-sequential packed bf16 weights: tasks are grouped 64 per wave;
// group g stores all CH chunks contiguously: uint4 index (g*CH + c)*64 + lane.
// -> each wave load instruction reads 1KB fully contiguous; successive chunks
// are +1KB. The whole per-wave stream is a single sequential ~CH KB burst.
// 4 accumulators + <=8 loads in flight (unroll 2) for ILP without spilling.
template<int CH>
__device__ __forceinline__ float dotpk(const ushort* __restrict__ wp, int t, const float* v) {
    const uint4* w = reinterpret_cast<const uint4*>(wp) + (t >> 6) * (CH * 64) + (t & 63);
    float s0 = 0.f, s1 = 0.f, s2 = 0.f, s3 = 0.f;
#pragma unroll 2
    for (int c = 0; c < (CH & ~3); c += 4) {
        uint4 u0 = w[(c + 0) * 64];
        uint4 u1 = w[(c + 1) * 64];
        uint4 u2 = w[(c + 2) * 64];
        uint4 u3 = w[(c + 3) * 64];
        s0 = acc8(u0, v + (c + 0) * 8, s0);
        s1 = acc8(u1, v + (c + 1) * 8, s1);
        s2 = acc8(u2, v + (c + 2) * 8, s2);
        s3 = acc8(u3, v + (c + 3) * 8, s3);
    }
    if (CH & 2) {
        constexpr int c0 = CH & ~3;
        uint4 u0 = w[(c0 + 0) * 64];
        uint4 u1 = w[(c0 + 1) * 64];
        s0 = acc8(u0, v + (c0 + 0) * 8, s0);
        s1 = acc8(u1, v + (c0 + 1) * 8, s1);
    }
    return (s0 + s1) + (s2 + s3);
}

// bf16 row in LDS (s_enc) . fp32 vector — unchanged path for score phase
__device__ __forceinline__ float dotbf(const ushort* __restrict__ wrow,
                                       const float* v, int k8) {
    const uint4* w = reinterpret_cast<const uint4*>(wrow);
    float s = 0.f;
#pragma unroll 8
    for (int k = 0; k < k8; ++k) {
        uint4 u = w[k];
        const float* vv = v + k * 8;
        s = fmaf(bflo(u.x), vv[0], s);
        s = fmaf(bfhi(u.x), vv[1], s);
        s = fmaf(bflo(u.y), vv[2], s);
        s = fmaf(bfhi(u.y), vv[3], s);
        s = fmaf(bflo(u.z), vv[4], s);
        s = fmaf(bfhi(u.z), vv[5], s);
        s = fmaf(bflo(u.w), vv[6], s);
        s = fmaf(bfhi(u.w), vv[7], s);
    }
    return s;
}

// fp32 source -> bf16 wave-group-sequential packed layout.
// dst elem i: i4=i>>3, e=i&7; lane=i4&63; q=i4>>6; c=q%CH; g=q/CH; t=g*64+lane;
// src index = (t/dA)*mA + (t%dA)*mB + c*8 + e
__global__ void pack_bf16_kernel(const float* __restrict__ src,
                                 ushort* __restrict__ dst,
                                 int NT, int CH, int dA, int mA, int mB) {
    int i = blockIdx.x * blockDim.x + threadIdx.x;
    int n = NT * CH * 8;
    if (i >= n) return;
    int i4 = i >> 3, e = i & 7;
    int lane = i4 & 63;
    int q = i4 >> 6;
    int c = q % CH;
    int g = q / CH;
    int t = g * 64 + lane;
    dst[i] = f2bf(src[(t / dA) * mA + (t % dA) * mB + c * 8 + e]);
}

// Persistent decoder: 1 block per batch element, enc[b] resident in LDS,
// bf16 packed weights L2-resident (2.9 MB < 4 MB/XCD).
// LDS (158.7KB) limits to 1 block/CU anyway, so allow 128 VGPRs (min 4 waves/EU)
// -> no spilling under the deeper load pipeline.
__global__ __launch_bounds__(TPB, 4) void decoder_persist(
    const float* __restrict__ dec_input,   // [B,T,MEL] fp32
    const float* __restrict__ enc_output,  // [B,L,D]  fp32 (converted in-kernel)
    const ushort* __restrict__ pre_w1, const float* __restrict__ pre_b1,
    const ushort* __restrict__ pre_w2, const float* __restrict__ pre_b2,
    const ushort* __restrict__ attn_wih, const ushort* __restrict__ attn_whh,
    const float* __restrict__ attn_bih, const float* __restrict__ attn_bhh,
    const ushort* __restrict__ proj1_w, const float* __restrict__ proj1_b,
    const ushort* __restrict__ rnn1_wih, const ushort* __restrict__ rnn1_whh,
    const float* __restrict__ rnn1_bih, const float* __restrict__ rnn1_bhh,
    const ushort* __restrict__ rnn2_wih, const ushort* __restrict__ rnn2_whh,
    const float* __restrict__ rnn2_bih, const float* __restrict__ rnn2_bhh,
    const ushort* __restrict__ proj2_w, const float* __restrict__ proj2_b,
    float* __restrict__ mel_out,   // [B, T*RED, MEL]
    float* __restrict__ align_out) // [B, L, T]
{
    const int b    = blockIdx.x;
    const int tid  = threadIdx.x;
    const int lane = tid & 63;
    const int wv   = tid >> 6;

    // LDS total ~158.5 KB (gfx950 has 160 KB/CU)
    __shared__ __align__(16) ushort s_enc[L_ * ENC_STRIDE];  // 135168 B
    __shared__ __align__(16) float A[1536];                  // partial buf A
    __shared__ __align__(16) float Bp[1536];                 // partial buf B
    __shared__ __align__(16) float s_frame[MEL_];
    __shared__ __align__(16) float s_x1[PRE_];
    __shared__ __align__(16) float s_x[E_];
    __shared__ __align__(16) float s_ha[D_];
    __shared__ __align__(16) float s_h1[D_];
    __shared__ __align__(16) float s_h2[D_];
    __shared__ __align__(16) float s_dec[D_];
    __shared__ __align__(16) float s_y1[D_];
    __shared__ __align__(16) float s_y2[D_];
    __shared__ __align__(16) float s_cat[2 * D_];
    __shared__ __align__(16) float s_al[L_];
    __shared__ float s_pmax[4];
    __shared__ float s_psum[4];

    // ---- load + convert enc[b] fp32 -> bf16 LDS (padded rows) ----
    {
        const float4* eb = reinterpret_cast<const float4*>(enc_output + (size_t)b * L_ * D_);
        for (int i = tid; i < (L_ * D_) / 4; i += TPB) {
            float4 f = eb[i];
            int row = i >> 6;   // 64 float4 per 256-elem row
            int c4  = i & 63;
            uint2 pk;
            pk.x = (unsigned)f2bf(f.x) | ((unsigned)f2bf(f.y) << 16);
            pk.y = (unsigned)f2bf(f.z) | ((unsigned)f2bf(f.w) << 16);
            *reinterpret_cast<uint2*>(s_enc + row * ENC_STRIDE + c4 * 4) = pk;
        }
    }
    if (tid < D_) { s_ha[tid] = 0.f; s_h1[tid] = 0.f; s_h2[tid] = 0.f; }
    __syncthreads();

    // GRU gate task phase: 3072 half-dots (K=128), 3 per thread, balanced.
    // task t<1536: wih row t>>1, half t&1; t>=1536: whh likewise (packed layouts match).
    auto gru_gates = [&](const ushort* wihP, const ushort* whhP,
                         const float* xin, const float* h) {
        for (int task = tid; task < 3072; task += TPB) {
            if (task < 1536) {
                A[task] = dotpk<16>(wihP, task, xin + (task & 1) * 128);
            } else {
                int u = task - 1536;
                Bp[u] = dotpk<16>(whhP, u, h + (u & 1) * 128);
            }
        }
    };
    auto gru_combine = [&](const float* bih, const float* bhh,
                           float* h, const float* xin, float* y) {
        if (tid < D_) {
            int t0 = tid;
            float gir = A[2 * t0] + A[2 * t0 + 1] + bih[t0];
            float giz = A[2 * (D_ + t0)] + A[2 * (D_ + t0) + 1] + bih[D_ + t0];
            float gin = A[2 * (2 * D_ + t0)] + A[2 * (2 * D_ + t0) + 1] + bih[2 * D_ + t0];
            float ghr = Bp[2 * t0] + Bp[2 * t0 + 1] + bhh[t0];
            float ghz = Bp[2 * (D_ + t0)] + Bp[2 * (D_ + t0) + 1] + bhh[D_ + t0];
            float ghn = Bp[2 * (2 * D_ + t0)] + Bp[2 * (2 * D_ + t0) + 1] + bhh[2 * D_ + t0];
            float r = sigmoidf_(gir + ghr);
            float z = sigmoidf_(giz + ghz);
            float n = tanhf(gin + r * ghn);
            float hn = (1.f - z) * n + z * h[t0];
            h[t0] = hn;
            y[t0] = xin[t0] + hn;
        }
    };

    for (int t = 0; t < T_; ++t) {
        // [1] frame
        if (tid < MEL_)
            s_frame[tid] = dec_input[((size_t)b * T_ + t) * MEL_ + tid];
        __syncthreads();

        // [2] prenet1: 256 rows, K=80 (CH=10)
        if (tid < PRE_)
            s_x1[tid] = fmaxf(dotpk<10>(pre_w1, tid, s_frame) + pre_b1[tid], 0.f);
        __syncthreads();

        // [3] prenet2 partials: 128 rows, K=256 split 8-way (32 elems = CH 4 each)
        {
            int p = tid >> 7, j = tid & 127;
            A[p * 128 + j] = dotpk<4>(pre_w2, tid, s_x1 + p * 32);
        }
        __syncthreads();
        // [4] prenet2 combine
        if (tid < E_) {
            float s = pre_b2[tid];
#pragma unroll
            for (int p = 0; p < 8; ++p) s += A[p * 128 + tid];
            s_x[tid] = fmaxf(s, 0.f);
        }
        __syncthreads();

        // [5] attn gates: gh halves -> Bp[0..1535]; gi full rows (K=128) -> A[0..767]
        for (int task = tid; task < 2304; task += TPB) {
            if (task < 1536) {
                Bp[task] = dotpk<16>(attn_whh, task, s_ha + (task & 1) * 128);
            } else {
                int r2 = task - 1536;
                A[r2] = dotpk<16>(attn_wih, r2, s_x);
            }
        }
        __syncthreads();
        // [6] attn GRU combine
        if (tid < D_) {
            float gir = A[tid] + attn_bih[tid];
            float giz = A[D_ + tid] + attn_bih[D_ + tid];
            float gin = A[2 * D_ + tid] + attn_bih[2 * D_ + tid];
            float ghr = Bp[2 * tid] + Bp[2 * tid + 1] + attn_bhh[tid];
            float ghz = Bp[2 * (D_ + tid)] + Bp[2 * (D_ + tid) + 1] + attn_bhh[D_ + tid];
            float ghn = Bp[2 * (2 * D_ + tid)] + Bp[2 * (2 * D_ + tid) + 1] + attn_bhh[2 * D_ + tid];
            float r = sigmoidf_(gir + ghr);
            float z = sigmoidf_(giz + ghz);
            float n = tanhf(gin + r * ghn);
            s_ha[tid] = (1.f - z) * n + z * s_ha[tid];
        }
        __syncthreads();

        // [7] scores partials: 256 rows x 4-way K-split over LDS enc
        {
            int p = tid >> 8, l = tid & 255;
            A[p * 256 + l] = dotbf(s_enc + l * ENC_STRIDE + p * 64, s_ha + p * 64, 8);
        }
        __syncthreads();
        float sc = 0.f, e = 0.f;
        // [8] finalize score + block max
        if (tid < L_) {
            sc = A[tid] + A[256 + tid] + A[512 + tid] + A[768 + tid];
            float m = sc;
            for (int o = 32; o > 0; o >>= 1) m = fmaxf(m, __shfl_xor(m, o, 64));
            if (lane == 0) s_pmax[wv] = m;
        }
        __syncthreads();
        // [9] exp + block sum
        if (tid < L_) {
            float mm = fmaxf(fmaxf(s_pmax[0], s_pmax[1]), fmaxf(s_pmax[2], s_pmax[3]));
            e = expf(sc - mm);
            float sm = e;
            for (int o = 32; o > 0; o >>= 1) sm += __shfl_xor(sm, o, 64);
            if (lane == 0) s_psum[wv] = sm;
        }
        __syncthreads();
        // [10] alignment
        if (tid < L_) {
            float denom = s_psum[0] + s_psum[1] + s_psum[2] + s_psum[3];
            float al = e / denom;
            s_al[tid] = al;
            align_out[((size_t)b * L_ + tid) * T_ + t] = al;
        }
        __syncthreads();

        // [11] ctx partials: 256 cols x 4-way L-split over LDS enc
        {
            int p = tid >> 8, d = tid & 255;
            const ushort* base = s_enc + (p * 64) * ENC_STRIDE + d;
            const float* alp = s_al + p * 64;
            float c = 0.f;
#pragma unroll 8
            for (int l = 0; l < 64; ++l)
                c = fmaf(alp[l], bfval(base[l * ENC_STRIDE]), c);
            A[p * 256 + d] = c;
        }
        __syncthreads();
        // [12] ctx combine -> cat
        if (tid < D_) {
            float c = A[tid] + A[256 + tid] + A[512 + tid] + A[768 + tid];
            s_cat[tid]      = c;
            s_cat[D_ + tid] = s_ha[tid];
        }
        __syncthreads();

        // [13] proj1 partials: 256 rows, K=512 split 4-way (CH=16 each)
        {
            int p = tid >> 8;
            A[tid] = dotpk<16>(proj1_w, tid, s_cat + p * 128);
        }
        __syncthreads();
        // [14] proj1 combine
        if (tid < D_)
            s_dec[tid] = A[tid] + A[256 + tid] + A[512 + tid] + A[768 + tid] + proj1_b[tid];
        __syncthreads();

        // [15][16] rnn1
        gru_gates(rnn1_wih, rnn1_whh, s_dec, s_h1);
        __syncthreads();
        gru_combine(rnn1_bih, rnn1_bhh, s_h1, s_dec, s_y1);
        __syncthreads();

        // [17][18] rnn2
        gru_gates(rnn2_wih, rnn2_whh, s_y1, s_h2);
        __syncthreads();
        gru_combine(rnn2_bih, rnn2_bhh, s_h2, s_y1, s_y2);
        __syncthreads();

        // [19] proj2 partials: 160 rows, K=256 split 4-way (640 tasks, CH=8)
        if (tid < 640) {
            A[tid] = dotpk<8>(proj2_w, tid, s_y2 + (tid & 3) * 64);
        }
        __syncthreads();
        // proj2 combine + mel store (no trailing barrier needed: next writes to A
        // are 2 barriers away)
        if (tid < MEL_ * RED_) {
            float s = A[4 * tid] + A[4 * tid + 1] + A[4 * tid + 2] + A[4 * tid + 3] + proj2_b[tid];
            mel_out[(size_t)b * (T_ * RED_ * MEL_) + (size_t)t * (MEL_ * RED_) + tid] = s;
        }
    }
}

extern "C" void kernel_launch(void* const* d_in, const int* in_sizes, int n_in,
                              void* d_out, int out_size, void* d_ws, size_t ws_size,
                              hipStream_t stream) {
    const float* dec_input = (const float*)d_in[0];
    const float* enc_output= (const float*)d_in[1];
    const float* pre_w1    = (const float*)d_in[2];
    const float* pre_b1    = (const float*)d_in[3];
    const float* pre_w2    = (const float*)d_in[4];
    const float* pre_b2    = (const float*)d_in[5];
    const float* attn_wih  = (const float*)d_in[6];
    const float* attn_whh  = (const float*)d_in[7];
    const float* attn_bih  = (const float*)d_in[8];
    const float* attn_bhh  = (const float*)d_in[9];
    const float* proj1_w   = (const float*)d_in[10];
    const float* proj1_b   = (const float*)d_in[11];
    const float* rnn1_wih  = (const float*)d_in[12];
    const float* rnn1_whh  = (const float*)d_in[13];
    const float* rnn1_bih  = (const float*)d_in[14];
    const float* rnn1_bhh  = (const float*)d_in[15];
    const float* rnn2_wih  = (const float*)d_in[16];
    const float* rnn2_whh  = (const float*)d_in[17];
    const float* rnn2_bih  = (const float*)d_in[18];
    const float* rnn2_bhh  = (const float*)d_in[19];
    const float* proj2_w   = (const float*)d_in[20];
    const float* proj2_b   = (const float*)d_in[21];

    float* mel   = (float*)d_out;
    float* align = (float*)d_out + (size_t)B_ * T_ * RED_ * MEL_;

    // bf16 packed weight scratch (element counts — identical totals as source)
    const int n_pre_w1   = PRE_ * MEL_;        // 256*80
    const int n_pre_w2   = E_ * PRE_;          // 128*256
    const int n_attn_wih = 3 * D_ * E_;        // 768*128
    const int n_attn_whh = 3 * D_ * D_;        // 768*256
    const int n_proj1    = D_ * 2 * D_;        // 256*512
    const int n_rnn_w    = 3 * D_ * D_;        // 768*256
    const int n_proj2    = MEL_ * RED_ * D_;   // 160*256

    ushort* w = (ushort*)d_ws;
    ushort* c_pre_w1   = w; w += n_pre_w1;
    ushort* c_pre_w2   = w; w += n_pre_w2;
    ushort* c_attn_wih = w; w += n_attn_wih;
    ushort* c_attn_whh = w; w += n_attn_whh;
    ushort* c_proj1    = w; w += n_proj1;
    ushort* c_rnn1_wih = w; w += n_rnn_w;
    ushort* c_rnn1_whh = w; w += n_rnn_w;
    ushort* c_rnn2_wih = w; w += n_rnn_w;
    ushort* c_rnn2_whh = w; w += n_rnn_w;
    ushort* c_proj2    = w; w += n_proj2;

    // Wave-group-sequential pack (see pack_bf16_kernel for index math)
    auto pack = [&](const float* src, ushort* dst, int NT, int CH, int dA, int mA, int mB) {
        int n = NT * CH * 8;
        pack_bf16_kernel<<<dim3((n + 255) / 256), dim3(256), 0, stream>>>(
            src, dst, NT, CH, dA, mA, mB);
    };
    pack(pre_w1,   c_pre_w1,   256,  10, 1,   80,  0);    // row t, K=80
    pack(pre_w2,   c_pre_w2,   1024, 4,  128, 32,  256);  // row=t&127, p=t>>7 (32-elem sub)
    pack(attn_wih, c_attn_wih, 768,  16, 1,   128, 0);    // row t, K=128
    pack(attn_whh, c_attn_whh, 1536, 16, 2,   256, 128);  // row=t>>1, half=t&1
    pack(proj1_w,  c_proj1,    1024, 16, 256, 128, 512);  // row=t&255, p=t>>8 (128-elem sub)
    pack(rnn1_wih, c_rnn1_wih, 1536, 16, 2,   256, 128);
    pack(rnn1_whh, c_rnn1_whh, 1536, 16, 2,   256, 128);
    pack(rnn2_wih, c_rnn2_wih, 1536, 16, 2,   256, 128);
    pack(rnn2_whh, c_rnn2_whh, 1536, 16, 2,   256, 128);
    pack(proj2_w,  c_proj2,    640,  8,  4,   256, 64);   // row=t>>2, p=t&3 (64-elem sub)

    decoder_persist<<<dim3(B_), dim3(TPB), 0, stream>>>(
        dec_input, enc_output,
        c_pre_w1, pre_b1, c_pre_w2, pre_b2,
        c_attn_wih, c_attn_whh, attn_bih, attn_bhh,
        c_proj1, proj1_b,
        c_rnn1_wih, c_rnn1_whh, rnn1_bih, rnn1_bhh,
        c_rnn2_wih, c_rnn2_whh, rnn2_bih, rnn2_bhh,
        c_proj2, proj2_b,
        mel, align);
}

// Round 3
// 15453.366 us; speedup vs baseline: 3.7272x; 1.3705x over previous
//
#include <hip/hip_runtime.h>
#include <cmath>

// Problem dims (fixed by reference)
#define B_   128
#define T_   500
#define MEL_ 80
#define RED_ 2
#define D_   256   // decoder dim
#define E_   128   // encoder/prenet-out dim
#define PRE_ 256   // prenet hidden
#define L_   256   // encoder length
#define TPB  1024
#define ENC_STRIDE 264   // padded ushort stride per enc row (264*2=528B, 16B aligned)
#define PTT  10    // timesteps per pre-pass block (500 % 10 == 0)

__device__ __forceinline__ float sigmoidf_(float x) { return 1.f / (1.f + expf(-x)); }
__device__ __forceinline__ float bflo(unsigned u) { return __uint_as_float(u << 16); }
__device__ __forceinline__ float bfhi(unsigned u) { return __uint_as_float(u & 0xFFFF0000u); }
__device__ __forceinline__ float bfval(ushort v) { return __uint_as_float(((unsigned)v) << 16); }
__device__ __forceinline__ ushort f2bf(float f) {
    unsigned u = __float_as_uint(f);
    return (ushort)((u + 0x7FFFu + ((u >> 16) & 1u)) >> 16);
}

// accumulate 8 bf16 (one uint4) against 8 fp32
__device__ __forceinline__ float acc8(uint4 u, const float* vv, float s) {
    s = fmaf(bflo(u.x), vv[0], s);
    s = fmaf(bfhi(u.x), vv[1], s);
    s = fmaf(bflo(u.y), vv[2], s);
    s = fmaf(bfhi(u.y), vv[3], s);
    s = fmaf(bflo(u.z), vv[4], s);
    s = fmaf(bfhi(u.z), vv[5], s);
    s = fmaf(bflo(u.w), vv[6], s);
    s = fmaf(bfhi(u.w), vv[7], s);
    return s;
}

// Wave-group-sequential packed bf16 weights: tasks are grouped 64 per wave;
// group g stores all CH chunks contiguously: uint4 index (g*CH + c)*64 + lane.
// -> each wave load instruction reads 1KB fully contiguous; successive chunks
// are +1KB. 4 accumulators + <=8 loads in flight (unroll 2): no spill at 64 VGPR.
template<int CH>
__device__ __forceinline__ float dotpk(const ushort* __restrict__ wp, int t, const float* v) {
    const uint4* w = reinterpret_cast<const uint4*>(wp) + (t >> 6) * (CH * 64) + (t & 63);
    float s0 = 0.f, s1 = 0.f, s2 = 0.f, s3 = 0.f;
#pragma unroll 2
    for (int c = 0; c < (CH & ~3); c += 4) {
        uint4 u0 = w[(c + 0) * 64];
        uint4 u1 = w[(c + 1) * 64];
        uint4 u2 = w[(c + 2) * 64];
        uint4 u3 = w[(c + 3) * 64];
        s0 = acc8(u0, v + (c + 0) * 8, s0);
        s1 = acc8(u1, v + (c + 1) * 8, s1);
        s2 = acc8(u2, v + (c + 2) * 8, s2);
        s3 = acc8(u3, v + (c + 3) * 8, s3);
    }
    if (CH & 2) {
        constexpr int c0 = CH & ~3;
        uint4 u0 = w[(c0 + 0) * 64];
        uint4 u1 = w[(c0 + 1) * 64];
        s0 = acc8(u0, v + (c0 + 0) * 8, s0);
        s1 = acc8(u1, v + (c0 + 1) * 8, s1);
    }
    return (s0 + s1) + (s2 + s3);
}

// bf16 row in LDS (s_enc) . fp32 vector — score phase
__device__ __forceinline__ float dotbf(const ushort* __restrict__ wrow,
                                       const float* v, int k8) {
    const uint4* w = reinterpret_cast<const uint4*>(wrow);
    float s = 0.f;
#pragma unroll 8
    for (int k = 0; k < k8; ++k) {
        uint4 u = w[k];
        const float* vv = v + k * 8;
        s = fmaf(bflo(u.x), vv[0], s);
        s = fmaf(bfhi(u.x), vv[1], s);
        s = fmaf(bflo(u.y), vv[2], s);
        s = fmaf(bfhi(u.y), vv[3], s);
        s = fmaf(bflo(u.z), vv[4], s);
        s = fmaf(bfhi(u.z), vv[5], s);
        s = fmaf(bflo(u.w), vv[6], s);
        s = fmaf(bfhi(u.w), vv[7], s);
    }
    return s;
}

// fp32 source -> bf16 wave-group-sequential packed layout.
// dst elem i: i4=i>>3, e=i&7; lane=i4&63; q=i4>>6; c=q%CH; g=q/CH; t=g*64+lane;
// src index = (t/dA)*mA + (t%dA)*mB + c*8 + e
__global__ void pack_bf16_kernel(const float* __restrict__ src,
                                 ushort* __restrict__ dst,
                                 int NT, int CH, int dA, int mA, int mB) {
    int i = blockIdx.x * blockDim.x + threadIdx.x;
    int n = NT * CH * 8;
    if (i >= n) return;
    int i4 = i >> 3, e = i & 7;
    int lane = i4 & 63;
    int q = i4 >> 6;
    int c = q % CH;
    int g = q / CH;
    int t = g * 64 + lane;
    dst[i] = f2bf(src[(t / dA) * mA + (t % dA) * mB + c * 8 + e]);
}

// -------- Pre-pass: prenet + attention-GRU input gates for ALL (b,t) --------
// gi[b,t,r] = attn_wih[r,:] @ relu(pre_w2 @ relu(pre_w1 @ frame + b1) + b2) + attn_bih[r]
// State-independent -> hoisted out of the 500-step serial loop. fp32 math,
// rounded once to bf16 on store. Removes 12% of step-loop MACs and 22% of the
// per-step L2 weight stream, plus 4 barriers/step.
__global__ __launch_bounds__(256) void prenet_gi_kernel(
    const float* __restrict__ dec_input,
    const float* __restrict__ pre_w1, const float* __restrict__ pre_b1,
    const float* __restrict__ pre_w2, const float* __restrict__ pre_b2,
    const float* __restrict__ attn_wih, const float* __restrict__ attn_bih,
    ushort* __restrict__ gi_out)   // [B, T, 3*D] bf16
{
    const int blk = blockIdx.x;            // B * (T/PTT) blocks
    const int b   = blk / (T_ / PTT);
    const int t0  = (blk % (T_ / PTT)) * PTT;
    const int tid = threadIdx.x;

    __shared__ float fr[PTT][MEL_];
    __shared__ float x1[PTT][PRE_];
    __shared__ float x2[PTT][E_];

    for (int i = tid; i < PTT * MEL_; i += 256) {
        int f = i / MEL_, m = i - f * MEL_;
        fr[f][m] = dec_input[((size_t)b * T_ + t0 + f) * MEL_ + m];
    }
    __syncthreads();

    // prenet1: row = tid (256 rows), K=80
    {
        float acc[PTT];
#pragma unroll
        for (int f = 0; f < PTT; ++f) acc[f] = pre_b1[tid];
        const float4* wr = reinterpret_cast<const float4*>(pre_w1 + tid * MEL_);
        for (int k4 = 0; k4 < MEL_ / 4; ++k4) {
            float4 w = wr[k4];
#pragma unroll
            for (int f = 0; f < PTT; ++f) {
                const float* fp = &fr[f][k4 * 4];
                acc[f] = fmaf(w.x, fp[0], fmaf(w.y, fp[1], fmaf(w.z, fp[2], fmaf(w.w, fp[3], acc[f]))));
            }
        }
#pragma unroll
        for (int f = 0; f < PTT; ++f) x1[f][tid] = fmaxf(acc[f], 0.f);
    }
    __syncthreads();

    // prenet2: row = tid (128 rows), K=256
    if (tid < E_) {
        float acc[PTT];
#pragma unroll
        for (int f = 0; f < PTT; ++f) acc[f] = pre_b2[tid];
        const float4* wr = reinterpret_cast<const float4*>(pre_w2 + tid * PRE_);
        for (int k4 = 0; k4 < PRE_ / 4; ++k4) {
            float4 w = wr[k4];
#pragma unroll
            for (int f = 0; f < PTT; ++f) {
                const float* fp = &x1[f][k4 * 4];
                acc[f] = fmaf(w.x, fp[0], fmaf(w.y, fp[1], fmaf(w.z, fp[2], fmaf(w.w, fp[3], acc[f]))));
            }
        }
#pragma unroll
        for (int f = 0; f < PTT; ++f) x2[f][tid] = fmaxf(acc[f], 0.f);
    }
    __syncthreads();

    // gi: rows tid, tid+256, tid+512 (768 rows), K=128; bias folded in
    for (int r = tid; r < 3 * D_; r += 256) {
        float acc[PTT];
#pragma unroll
        for (int f = 0; f < PTT; ++f) acc[f] = attn_bih[r];
        const float4* wr = reinterpret_cast<const float4*>(attn_wih + r * E_);
        for (int k4 = 0; k4 < E_ / 4; ++k4) {
            float4 w = wr[k4];
#pragma unroll
            for (int f = 0; f < PTT; ++f) {
                const float* fp = &x2[f][k4 * 4];
                acc[f] = fmaf(w.x, fp[0], fmaf(w.y, fp[1], fmaf(w.z, fp[2], fmaf(w.w, fp[3], acc[f]))));
            }
        }
#pragma unroll
        for (int f = 0; f < PTT; ++f)
            gi_out[((size_t)b * T_ + t0 + f) * (3 * D_) + r] = f2bf(acc[f]);
    }
}

// Persistent decoder: 1 block per batch element, enc[b] resident in LDS,
// bf16 packed weights L2-resident. LDS (158.7KB) limits to 1 block/CU, so
// allow 128 VGPRs (min 4 waves/EU) — no spilling.
// gi_g != nullptr: prenet + attn input-gates precomputed (phases [1]-[4] and
// the wih part of [5] skipped).
__global__ __launch_bounds__(TPB, 4) void decoder_persist(
    const float* __restrict__ dec_input,   // [B,T,MEL] fp32
    const float* __restrict__ enc_output,  // [B,L,D]  fp32 (converted in-kernel)
    const ushort* __restrict__ pre_w1, const float* __restrict__ pre_b1,
    const ushort* __restrict__ pre_w2, const float* __restrict__ pre_b2,
    const ushort* __restrict__ attn_wih, const ushort* __restrict__ attn_whh,
    const float* __restrict__ attn_bih, const float* __restrict__ attn_bhh,
    const ushort* __restrict__ proj1_w, const float* __restrict__ proj1_b,
    const ushort* __restrict__ rnn1_wih, const ushort* __restrict__ rnn1_whh,
    const float* __restrict__ rnn1_bih, const float* __restrict__ rnn1_bhh,
    const ushort* __restrict__ rnn2_wih, const ushort* __restrict__ rnn2_whh,
    const float* __restrict__ rnn2_bih, const float* __restrict__ rnn2_bhh,
    const ushort* __restrict__ proj2_w, const float* __restrict__ proj2_b,
    const ushort* __restrict__ gi_g,       // [B,T,3*D] bf16 or nullptr
    float* __restrict__ mel_out,   // [B, T*RED, MEL]
    float* __restrict__ align_out) // [B, L, T]
{
    const int b    = blockIdx.x;
    const int tid  = threadIdx.x;
    const int lane = tid & 63;
    const int wv   = tid >> 6;

    // LDS total ~158.5 KB (gfx950 has 160 KB/CU)
    __shared__ __align__(16) ushort s_enc[L_ * ENC_STRIDE];  // 135168 B
    __shared__ __align__(16) float A[1536];                  // partial buf A
    __shared__ __align__(16) float Bp[1536];                 // partial buf B
    __shared__ __align__(16) float s_frame[MEL_];
    __shared__ __align__(16) float s_x1[PRE_];
    __shared__ __align__(16) float s_x[E_];
    __shared__ __align__(16) float s_ha[D_];
    __shared__ __align__(16) float s_h1[D_];
    __shared__ __align__(16) float s_h2[D_];
    __shared__ __align__(16) float s_dec[D_];
    __shared__ __align__(16) float s_y1[D_];
    __shared__ __align__(16) float s_y2[D_];
    __shared__ __align__(16) float s_cat[2 * D_];
    __shared__ __align__(16) float s_al[L_];
    __shared__ float s_pmax[4];
    __shared__ float s_psum[4];

    // ---- load + convert enc[b] fp32 -> bf16 LDS (padded rows) ----
    {
        const float4* eb = reinterpret_cast<const float4*>(enc_output + (size_t)b * L_ * D_);
        for (int i = tid; i < (L_ * D_) / 4; i += TPB) {
            float4 f = eb[i];
            int row = i >> 6;   // 64 float4 per 256-elem row
            int c4  = i & 63;
            uint2 pk;
            pk.x = (unsigned)f2bf(f.x) | ((unsigned)f2bf(f.y) << 16);
            pk.y = (unsigned)f2bf(f.z) | ((unsigned)f2bf(f.w) << 16);
            *reinterpret_cast<uint2*>(s_enc + row * ENC_STRIDE + c4 * 4) = pk;
        }
    }
    if (tid < D_) { s_ha[tid] = 0.f; s_h1[tid] = 0.f; s_h2[tid] = 0.f; }
    __syncthreads();

    // GRU gate task phase: 3072 half-dots (K=128), 3 per thread, balanced.
    auto gru_gates = [&](const ushort* wihP, const ushort* whhP,
                         const float* xin, const float* h) {
        for (int task = tid; task < 3072; task += TPB) {
            if (task < 1536) {
                A[task] = dotpk<16>(wihP, task, xin + (task & 1) * 128);
            } else {
                int u = task - 1536;
                Bp[u] = dotpk<16>(whhP, u, h + (u & 1) * 128);
            }
        }
    };
    auto gru_combine = [&](const float* bih, const float* bhh,
                           float* h, const float* xin, float* y) {
        if (tid < D_) {
            int t0 = tid;
            float gir = A[2 * t0] + A[2 * t0 + 1] + bih[t0];
            float giz = A[2 * (D_ + t0)] + A[2 * (D_ + t0) + 1] + bih[D_ + t0];
            float gin = A[2 * (2 * D_ + t0)] + A[2 * (2 * D_ + t0) + 1] + bih[2 * D_ + t0];
            float ghr = Bp[2 * t0] + Bp[2 * t0 + 1] + bhh[t0];
            float ghz = Bp[2 * (D_ + t0)] + Bp[2 * (D_ + t0) + 1] + bhh[D_ + t0];
            float ghn = Bp[2 * (2 * D_ + t0)] + Bp[2 * (2 * D_ + t0) + 1] + bhh[2 * D_ + t0];
            float r = sigmoidf_(gir + ghr);
            float z = sigmoidf_(giz + ghz);
            float n = tanhf(gin + r * ghn);
            float hn = (1.f - z) * n + z * h[t0];
            h[t0] = hn;
            y[t0] = xin[t0] + hn;
        }
    };

    for (int t = 0; t < T_; ++t) {
        if (gi_g) {
            // [5'] attn gh only: 1536 half-dots (K=128) over whh
            for (int task = tid; task < 1536; task += TPB)
                Bp[task] = dotpk<16>(attn_whh, task, s_ha + (task & 1) * 128);
            __syncthreads();
        } else {
            // [1] frame
            if (tid < MEL_)
                s_frame[tid] = dec_input[((size_t)b * T_ + t) * MEL_ + tid];
            __syncthreads();
            // [2] prenet1: 256 rows, K=80 (CH=10)
            if (tid < PRE_)
                s_x1[tid] = fmaxf(dotpk<10>(pre_w1, tid, s_frame) + pre_b1[tid], 0.f);
            __syncthreads();
            // [3] prenet2 partials: 128 rows, K=256 split 8-way
            {
                int p = tid >> 7, j = tid & 127;
                A[p * 128 + j] = dotpk<4>(pre_w2, tid, s_x1 + p * 32);
            }
            __syncthreads();
            // [4] prenet2 combine
            if (tid < E_) {
                float s = pre_b2[tid];
#pragma unroll
                for (int p = 0; p < 8; ++p) s += A[p * 128 + tid];
                s_x[tid] = fmaxf(s, 0.f);
            }
            __syncthreads();
            // [5] attn gates: gh halves -> Bp; gi full rows -> A
            for (int task = tid; task < 2304; task += TPB) {
                if (task < 1536) {
                    Bp[task] = dotpk<16>(attn_whh, task, s_ha + (task & 1) * 128);
                } else {
                    int r2 = task - 1536;
                    A[r2] = dotpk<16>(attn_wih, r2, s_x);
                }
            }
            __syncthreads();
        }

        // [6] attn GRU combine
        if (tid < D_) {
            float gir, giz, gin;
            if (gi_g) {
                const ushort* gp = gi_g + ((size_t)b * T_ + t) * (3 * D_);
                gir = bfval(gp[tid]);
                giz = bfval(gp[D_ + tid]);
                gin = bfval(gp[2 * D_ + tid]);
            } else {
                gir = A[tid] + attn_bih[tid];
                giz = A[D_ + tid] + attn_bih[D_ + tid];
                gin = A[2 * D_ + tid] + attn_bih[2 * D_ + tid];
            }
            float ghr = Bp[2 * tid] + Bp[2 * tid + 1] + attn_bhh[tid];
            float ghz = Bp[2 * (D_ + tid)] + Bp[2 * (D_ + tid) + 1] + attn_bhh[D_ + tid];
            float ghn = Bp[2 * (2 * D_ + tid)] + Bp[2 * (2 * D_ + tid) + 1] + attn_bhh[2 * D_ + tid];
            float r = sigmoidf_(gir + ghr);
            float z = sigmoidf_(giz + ghz);
            float n = tanhf(gin + r * ghn);
            s_ha[tid] = (1.f - z) * n + z * s_ha[tid];
        }
        __syncthreads();

        // [7] scores partials: 256 rows x 4-way K-split over LDS enc
        {
            int p = tid >> 8, l = tid & 255;
            A[p * 256 + l] = dotbf(s_enc + l * ENC_STRIDE + p * 64, s_ha + p * 64, 8);
        }
        __syncthreads();
        float sc = 0.f, e = 0.f;
        // [8] finalize score + block max
        if (tid < L_) {
            sc = A[tid] + A[256 + tid] + A[512 + tid] + A[768 + tid];
            float m = sc;
            for (int o = 32; o > 0; o >>= 1) m = fmaxf(m, __shfl_xor(m, o, 64));
            if (lane == 0) s_pmax[wv] = m;
        }
        __syncthreads();
        // [9] exp + block sum
        if (tid < L_) {
            float mm = fmaxf(fmaxf(s_pmax[0], s_pmax[1]), fmaxf(s_pmax[2], s_pmax[3]));
            e = expf(sc - mm);
            float sm = e;
            for (int o = 32; o > 0; o >>= 1) sm += __shfl_xor(sm, o, 64);
            if (lane == 0) s_psum[wv] = sm;
        }
        __syncthreads();
        // [10] alignment
        if (tid < L_) {
            float denom = s_psum[0] + s_psum[1] + s_psum[2] + s_psum[3];
            float al = e / denom;
            s_al[tid] = al;
            align_out[((size_t)b * L_ + tid) * T_ + t] = al;
        }
        __syncthreads();

        // [11] ctx partials: 256 cols x 4-way L-split over LDS enc
        {
            int p = tid >> 8, d = tid & 255;
            const ushort* base = s_enc + (p * 64) * ENC_STRIDE + d;
            const float* alp = s_al + p * 64;
            float c = 0.f;
#pragma unroll 8
            for (int l = 0; l < 64; ++l)
                c = fmaf(alp[l], bfval(base[l * ENC_STRIDE]), c);
            A[p * 256 + d] = c;
        }
        __syncthreads();
        // [12] ctx combine -> cat
        if (tid < D_) {
            float c = A[tid] + A[256 + tid] + A[512 + tid] + A[768 + tid];
            s_cat[tid]      = c;
            s_cat[D_ + tid] = s_ha[tid];
        }
        __syncthreads();

        // [13] proj1 partials: 256 rows, K=512 split 4-way (CH=16 each)
        {
            int p = tid >> 8;
            A[tid] = dotpk<16>(proj1_w, tid, s_cat + p * 128);
        }
        __syncthreads();
        // [14] proj1 combine
        if (tid < D_)
            s_dec[tid] = A[tid] + A[256 + tid] + A[512 + tid] + A[768 + tid] + proj1_b[tid];
        __syncthreads();

        // [15][16] rnn1
        gru_gates(rnn1_wih, rnn1_whh, s_dec, s_h1);
        __syncthreads();
        gru_combine(rnn1_bih, rnn1_bhh, s_h1, s_dec, s_y1);
        __syncthreads();

        // [17][18] rnn2
        gru_gates(rnn2_wih, rnn2_whh, s_y1, s_h2);
        __syncthreads();
        gru_combine(rnn2_bih, rnn2_bhh, s_h2, s_y1, s_y2);
        __syncthreads();

        // [19] proj2 partials: 160 rows, K=256 split 4-way (640 tasks, CH=8)
        if (tid < 640) {
            A[tid] = dotpk<8>(proj2_w, tid, s_y2 + (tid & 3) * 64);
        }
        __syncthreads();
        // proj2 combine + mel store (no trailing barrier needed: the next phase
        // writes only Bp / reads s_ha, both disjoint; the barrier after it
        // orders this combine before A is rewritten)
        if (tid < MEL_ * RED_) {
            float s = A[4 * tid] + A[4 * tid + 1] + A[4 * tid + 2] + A[4 * tid + 3] + proj2_b[tid];
            mel_out[(size_t)b * (T_ * RED_ * MEL_) + (size_t)t * (MEL_ * RED_) + tid] = s;
        }
    }
}

extern "C" void kernel_launch(void* const* d_in, const int* in_sizes, int n_in,
                              void* d_out, int out_size, void* d_ws, size_t ws_size,
                              hipStream_t stream) {
    const float* dec_input = (const float*)d_in[0];
    const float* enc_output= (const float*)d_in[1];
    const float* pre_w1    = (const float*)d_in[2];
    const float* pre_b1    = (const float*)d_in[3];
    const float* pre_w2    = (const float*)d_in[4];
    const float* pre_b2    = (const float*)d_in[5];
    const float* attn_wih  = (const float*)d_in[6];
    const float* attn_whh  = (const float*)d_in[7];
    const float* attn_bih  = (const float*)d_in[8];
    const float* attn_bhh  = (const float*)d_in[9];
    const float* proj1_w   = (const float*)d_in[10];
    const float* proj1_b   = (const float*)d_in[11];
    const float* rnn1_wih  = (const float*)d_in[12];
    const float* rnn1_whh  = (const float*)d_in[13];
    const float* rnn1_bih  = (const float*)d_in[14];
    const float* rnn1_bhh  = (const float*)d_in[15];
    const float* rnn2_wih  = (const float*)d_in[16];
    const float* rnn2_whh  = (const float*)d_in[17];
    const float* rnn2_bih  = (const float*)d_in[18];
    const float* rnn2_bhh  = (const float*)d_in[19];
    const float* proj2_w   = (const float*)d_in[20];
    const float* proj2_b   = (const float*)d_in[21];

    float* mel   = (float*)d_out;
    float* align = (float*)d_out + (size_t)B_ * T_ * RED_ * MEL_;

    // bf16 packed weight scratch (element counts)
    const int n_pre_w1   = PRE_ * MEL_;        // 20480
    const int n_pre_w2   = E_ * PRE_;          // 32768
    const int n_attn_wih = 3 * D_ * E_;        // 98304
    const int n_attn_whh = 3 * D_ * D_;        // 196608
    const int n_proj1    = D_ * 2 * D_;        // 131072
    const int n_rnn_w    = 3 * D_ * D_;        // 196608
    const int n_proj2    = MEL_ * RED_ * D_;   // 40960

    ushort* w = (ushort*)d_ws;
    ushort* c_pre_w1   = w; w += n_pre_w1;
    ushort* c_pre_w2   = w; w += n_pre_w2;
    ushort* c_attn_wih = w; w += n_attn_wih;
    ushort* c_attn_whh = w; w += n_attn_whh;
    ushort* c_proj1    = w; w += n_proj1;
    ushort* c_rnn1_wih = w; w += n_rnn_w;
    ushort* c_rnn1_whh = w; w += n_rnn_w;
    ushort* c_rnn2_wih = w; w += n_rnn_w;
    ushort* c_rnn2_whh = w; w += n_rnn_w;
    ushort* c_proj2    = w; w += n_proj2;

    // gi precompute buffer (bf16 [B,T,3*D]) directly after packed weights
    const size_t n_gi = (size_t)B_ * T_ * 3 * D_;                 // 49,152,000
    const size_t packed_bytes = (size_t)(w - (ushort*)d_ws) * sizeof(ushort);
    const size_t need = packed_bytes + n_gi * sizeof(ushort);     // ~101 MB
    ushort* c_gi = (ws_size >= need) ? w : nullptr;

    // Wave-group-sequential pack (see pack_bf16_kernel for index math)
    auto pack = [&](const float* src, ushort* dst, int NT, int CH, int dA, int mA, int mB) {
        int n = NT * CH * 8;
        pack_bf16_kernel<<<dim3((n + 255) / 256), dim3(256), 0, stream>>>(
            src, dst, NT, CH, dA, mA, mB);
    };
    pack(pre_w1,   c_pre_w1,   256,  10, 1,   80,  0);    // row t, K=80
    pack(pre_w2,   c_pre_w2,   1024, 4,  128, 32,  256);  // row=t&127, p=t>>7
    pack(attn_wih, c_attn_wih, 768,  16, 1,   128, 0);    // row t, K=128
    pack(attn_whh, c_attn_whh, 1536, 16, 2,   256, 128);  // row=t>>1, half=t&1
    pack(proj1_w,  c_proj1,    1024, 16, 256, 128, 512);  // row=t&255, p=t>>8
    pack(rnn1_wih, c_rnn1_wih, 1536, 16, 2,   256, 128);
    pack(rnn1_whh, c_rnn1_whh, 1536, 16, 2,   256, 128);
    pack(rnn2_wih, c_rnn2_wih, 1536, 16, 2,   256, 128);
    pack(rnn2_whh, c_rnn2_whh, 1536, 16, 2,   256, 128);
    pack(proj2_w,  c_proj2,    640,  8,  4,   256, 64);   // row=t>>2, p=t&3

    if (c_gi) {
        prenet_gi_kernel<<<dim3(B_ * (T_ / PTT)), dim3(256), 0, stream>>>(
            dec_input, pre_w1, pre_b1, pre_w2, pre_b2, attn_wih, attn_bih, c_gi);
    }

    decoder_persist<<<dim3(B_), dim3(TPB), 0, stream>>>(
        dec_input, enc_output,
        c_pre_w1, pre_b1, c_pre_w2, pre_b2,
        c_attn_wih, c_attn_whh, attn_bih, attn_bhh,
        c_proj1, proj1_b,
        c_rnn1_wih, c_rnn1_whh, rnn1_bih, rnn1_bhh,
        c_rnn2_wih, c_rnn2_whh, rnn2_bih, rnn2_bhh,
        c_proj2, proj2_b,
        c_gi,
        mel, align);
}